// Round 11
// baseline (200.325 us; speedup 1.0000x reference)
//
#include <hip/hip_runtime.h>
#include <hip/hip_bf16.h>
#include <cstddef>
#include <cstdint>

#define D_MODEL   512
#define FF        2048
#define D_STATE   128
#define D_INNER   1024
#define HEADDIM   64
#define NHEADS    16
#define CONV_DIM  1280
#define D_IN_PROJ 2320
#define NPJ_PAD   2432      // D_IN_PROJ padded to 128
#define B_SZ      2
#define SEQ       2048
#define NTOK      (B_SZ*SEQ)   // 4096
#define LCH       32
#define NCHUNK    (SEQ/LCH)    // 64
#define NCID      (B_SZ*NHEADS*NCHUNK)  // 2048
#define LN_SLICE  ((size_t)NTOK*D_MODEL)

typedef __attribute__((ext_vector_type(8))) short short8;
typedef __attribute__((ext_vector_type(4))) float f32x4;

__device__ __forceinline__ float sigmoid_f(float x){ return 1.0f/(1.0f+expf(-x)); }
__device__ __forceinline__ float gelu_f(float x){ return 0.5f*x*(1.0f+erff(x*0.70710678118654752f)); }

__device__ __forceinline__ unsigned short bf16bits(float f){
  __hip_bfloat16 h = __float2bfloat16(f);
  return *reinterpret_cast<unsigned short*>(&h);
}
__device__ __forceinline__ float bf2f(unsigned short u){ return __uint_as_float(((unsigned)u)<<16); }
__device__ __forceinline__ float blo(unsigned u){ return __uint_as_float(u<<16); }
__device__ __forceinline__ float bhi(unsigned u){ return __uint_as_float(u & 0xffff0000u); }
__device__ __forceinline__ unsigned bfpack2(float a, float b){
  return (unsigned)bf16bits(a) | ((unsigned)bf16bits(b)<<16);
}

__device__ __forceinline__ void gload16(const void* g, void* l){
  __builtin_amdgcn_global_load_lds((const __attribute__((address_space(1))) void*)g,
                                   (__attribute__((address_space(3))) void*)l, 16, 0, 0);
}

union U4S8 { uint4 v; unsigned short s[8]; };

// ============ m97-structure GEMM: BM=128,BN=128,BK=64, 4 waves of 64x64 ======
template<int EPI, typename OT>   // EPI 0: none, 1: +bias, 2: gelu(.+bias)
__global__ __launch_bounds__(256)
void gemm128(const __hip_bfloat16* __restrict__ A, const __hip_bfloat16* __restrict__ Bt,
             const float* __restrict__ bias, OT* __restrict__ C,
             int N, int K, int ldc)
{
  __shared__ char AsRaw[128*128];
  __shared__ char BsRaw[128*128];

  const int t    = threadIdx.x;
  const int bm   = blockIdx.y * 128;
  const int bn   = blockIdx.x * 128;
  const int lane = t & 63;
  const int wid  = t >> 6;
  const int wr   = wid >> 1;
  const int wc   = wid & 1;
  const int lrow = lane & 15;
  const int lkb  = (lane >> 4) * 16;
  const int sw   = (lrow & 7) << 4;

  const int rA  = t >> 3;
  const int cbA = (t & 7) * 16;
  const int scb = cbA ^ ((rA & 7) << 4);
  const size_t strideA = (size_t)K * 2;
  const char* aSrc = (const char*)A  + (size_t)(bm + rA) * strideA + scb;
  const char* bSrc = (const char*)Bt + (size_t)(bn + rA) * strideA + scb;
  char* aDst = AsRaw + wid * 1024;
  char* bDst = BsRaw + wid * 1024;

  f32x4 acc[4][4];
  #pragma unroll
  for (int m=0;m<4;m++)
    #pragma unroll
    for (int n=0;n<4;n++) acc[m][n] = (f32x4){0.f,0.f,0.f,0.f};

  const char* ArP = AsRaw + (wr*64 + lrow) * 128;
  const char* BrP = BsRaw + (wc*64 + lrow) * 128;

  for (int k0 = 0; k0 < K; k0 += 64) {
    const size_t ko = (size_t)k0 * 2;
    gload16(aSrc + ko,               aDst);
    gload16(aSrc + ko + 32*strideA,  aDst + 4096);
    gload16(aSrc + ko + 64*strideA,  aDst + 8192);
    gload16(aSrc + ko + 96*strideA,  aDst + 12288);
    gload16(bSrc + ko,               bDst);
    gload16(bSrc + ko + 32*strideA,  bDst + 4096);
    gload16(bSrc + ko + 64*strideA,  bDst + 8192);
    gload16(bSrc + ko + 96*strideA,  bDst + 12288);
    __syncthreads();
    #pragma unroll
    for (int kk = 0; kk < 2; ++kk) {
      const int kb = (kk*64 + lkb) ^ sw;
      short8 a0 = *(const short8*)(ArP + 0*2048 + kb);
      short8 a1 = *(const short8*)(ArP + 1*2048 + kb);
      short8 a2 = *(const short8*)(ArP + 2*2048 + kb);
      short8 a3 = *(const short8*)(ArP + 3*2048 + kb);
      short8 b0 = *(const short8*)(BrP + 0*2048 + kb);
      short8 b1 = *(const short8*)(BrP + 1*2048 + kb);
      short8 b2 = *(const short8*)(BrP + 2*2048 + kb);
      short8 b3 = *(const short8*)(BrP + 3*2048 + kb);
      #pragma unroll
      for (int m=0;m<4;m++){
        short8 am = (m==0)?a0:(m==1)?a1:(m==2)?a2:a3;
        acc[m][0] = __builtin_amdgcn_mfma_f32_16x16x32_bf16(am, b0, acc[m][0], 0,0,0);
        acc[m][1] = __builtin_amdgcn_mfma_f32_16x16x32_bf16(am, b1, acc[m][1], 0,0,0);
        acc[m][2] = __builtin_amdgcn_mfma_f32_16x16x32_bf16(am, b2, acc[m][2], 0,0,0);
        acc[m][3] = __builtin_amdgcn_mfma_f32_16x16x32_bf16(am, b3, acc[m][3], 0,0,0);
      }
    }
    __syncthreads();
  }

  const int orow0 = bm + wr*64 + (lane >> 4) * 4;
  const int ocol0 = bn + wc*64 + lrow;
  #pragma unroll
  for (int n=0;n<4;n++) {
    const int col = ocol0 + n*16;
    if (col >= N) continue;
    const float bv = (EPI>=1) ? bias[col] : 0.f;
    #pragma unroll
    for (int m=0;m<4;m++) {
      #pragma unroll
      for (int j=0;j<4;j++) {
        float v = acc[m][n][j] + bv;
        if (EPI==2) v = gelu_f(v);
        OT* cp = C + (size_t)(orow0 + m*16 + j)*ldc + col;
        if constexpr (sizeof(OT)==2) *cp = __float2bfloat16(v); else *cp = v;
      }
    }
  }
}

// ==== 128x64 GEMM with split-K (blockIdx.z): C_z = A[:,z*K/s:(z+1)K/s]@Bt^T ===
template<int EPI, typename OT>
__global__ __launch_bounds__(256)
void gemm_bf16(const __hip_bfloat16* __restrict__ A, const __hip_bfloat16* __restrict__ Bt,
               const float* __restrict__ bias, OT* __restrict__ C,
               int N, int K, int ldc, int M, int nsplit)
{
  __shared__ char AsRaw[128*128];
  __shared__ char BsRaw[64*128];

  const int t    = threadIdx.x;
  const int bm   = blockIdx.y * 128;
  const int bn   = blockIdx.x * 64;
  const int z    = blockIdx.z;
  const int Kloop= K / nsplit;
  A += (size_t)z * Kloop;
  Bt += (size_t)z * Kloop;
  C += (size_t)z * M * ldc;

  const int lane = t & 63;
  const int wid  = t >> 6;
  const int wr   = wid >> 1;
  const int wc   = wid & 1;
  const int lrow = lane & 15;
  const int lkb  = (lane >> 4) * 16;
  const int sw   = (lrow & 7) << 4;

  const int rA  = t >> 3;
  const int cbA = (t & 7) * 16;
  const int scb = cbA ^ ((rA & 7) << 4);
  const size_t strideA = (size_t)K * 2;
  const char* aSrc = (const char*)A  + (size_t)(bm + rA) * strideA + scb;
  const char* bSrc = (const char*)Bt + (size_t)(bn + rA) * strideA + scb;
  char* aDst = AsRaw + wid * 1024;
  char* bDst = BsRaw + wid * 1024;

  f32x4 acc[4][2];
  #pragma unroll
  for (int m=0;m<4;m++)
    #pragma unroll
    for (int n=0;n<2;n++) acc[m][n] = (f32x4){0.f,0.f,0.f,0.f};

  const char* ArP = AsRaw + (wr*64 + lrow) * 128;
  const char* BrP = BsRaw + (wc*32 + lrow) * 128;

  for (int k0 = 0; k0 < Kloop; k0 += 64) {
    const size_t ko = (size_t)k0 * 2;
    gload16(aSrc + ko,               aDst);
    gload16(aSrc + ko + 32*strideA,  aDst + 4096);
    gload16(aSrc + ko + 64*strideA,  aDst + 8192);
    gload16(aSrc + ko + 96*strideA,  aDst + 12288);
    gload16(bSrc + ko,               bDst);
    gload16(bSrc + ko + 32*strideA,  bDst + 4096);
    __syncthreads();
    #pragma unroll
    for (int kk = 0; kk < 2; ++kk) {
      const int kb = (kk*64 + lkb) ^ sw;
      short8 a0 = *(const short8*)(ArP + 0*2048 + kb);
      short8 a1 = *(const short8*)(ArP + 1*2048 + kb);
      short8 a2 = *(const short8*)(ArP + 2*2048 + kb);
      short8 a3 = *(const short8*)(ArP + 3*2048 + kb);
      short8 b0 = *(const short8*)(BrP + 0*2048 + kb);
      short8 b1 = *(const short8*)(BrP + 1*2048 + kb);
      acc[0][0] = __builtin_amdgcn_mfma_f32_16x16x32_bf16(a0, b0, acc[0][0], 0,0,0);
      acc[1][0] = __builtin_amdgcn_mfma_f32_16x16x32_bf16(a1, b0, acc[1][0], 0,0,0);
      acc[2][0] = __builtin_amdgcn_mfma_f32_16x16x32_bf16(a2, b0, acc[2][0], 0,0,0);
      acc[3][0] = __builtin_amdgcn_mfma_f32_16x16x32_bf16(a3, b0, acc[3][0], 0,0,0);
      acc[0][1] = __builtin_amdgcn_mfma_f32_16x16x32_bf16(a0, b1, acc[0][1], 0,0,0);
      acc[1][1] = __builtin_amdgcn_mfma_f32_16x16x32_bf16(a1, b1, acc[1][1], 0,0,0);
      acc[2][1] = __builtin_amdgcn_mfma_f32_16x16x32_bf16(a2, b1, acc[2][1], 0,0,0);
      acc[3][1] = __builtin_amdgcn_mfma_f32_16x16x32_bf16(a3, b1, acc[3][1], 0,0,0);
    }
    __syncthreads();
  }

  const int orow0 = bm + wr*64 + (lane >> 4) * 4;
  const int ocol0 = bn + wc*32 + lrow;
  #pragma unroll
  for (int n=0;n<2;n++) {
    const int col = ocol0 + n*16;
    if (col >= N) continue;
    const float bv = (EPI>=1 && z==0) ? bias[col] : 0.f;
    #pragma unroll
    for (int m=0;m<4;m++) {
      #pragma unroll
      for (int j=0;j<4;j++) {
        float v = acc[m][n][j] + bv;
        if (EPI==2) v = gelu_f(v);
        OT* cp = C + (size_t)(orow0 + m*16 + j)*ldc + col;
        if constexpr (sizeof(OT)==2) *cp = __float2bfloat16(v); else *cp = v;
      }
    }
  }
}

// ======= prep_all: all 4 weight transposes + tgt->bf16 in ONE dispatch =======
__device__ __forceinline__ void tr_tile(const float* __restrict__ in,
                                        __hip_bfloat16* __restrict__ out,
                                        int K, int N, int Npad, int bx, int by)
{
  __shared__ float tbuf[32][33];
  const int tx = threadIdx.x & 31, ty = threadIdx.x >> 5;
  #pragma unroll
  for (int u=0;u<4;u++){
    int k = by*32 + ty + u*8;
    int n = bx*32 + tx;
    tbuf[ty+u*8][tx] = (n < N) ? in[(size_t)k*N + n] : 0.f;
  }
  __syncthreads();
  #pragma unroll
  for (int u=0;u<4;u++){
    int n = bx*32 + ty + u*8;
    int k = by*32 + tx;
    if (n < Npad) out[(size_t)n*K + k] = __float2bfloat16(tbuf[tx][ty+u*8]);
  }
}

__global__ __launch_bounds__(256)
void prep_all(const float* __restrict__ tgt, __hip_bfloat16* __restrict__ tgt_bf,
              const float* __restrict__ W_in,  __hip_bfloat16* __restrict__ Wint,
              const float* __restrict__ W_out, __hip_bfloat16* __restrict__ Woutt,
              const float* __restrict__ W1,    __hip_bfloat16* __restrict__ W1t,
              const float* __restrict__ W2,    __hip_bfloat16* __restrict__ W2t)
{
  int bid = blockIdx.x;
  if (bid < 2048) {             // tgt convert: 2M elems, 1024/block
    int i = bid*1024 + threadIdx.x*4;
    float4 v = *(const float4*)(tgt + i);
    *(uint2*)(tgt_bf + i) = (uint2){bfpack2(v.x,v.y), bfpack2(v.z,v.w)};
    return;
  }
  bid -= 2048;
  if (bid < 76*16) { tr_tile(W_in, Wint, D_MODEL, D_IN_PROJ, NPJ_PAD, bid%76, bid/76); return; }
  bid -= 76*16;
  if (bid < 16*32) { tr_tile(W_out, Woutt, D_INNER, D_MODEL, D_MODEL, bid%16, bid/16); return; }
  bid -= 16*32;
  if (bid < 64*16) { tr_tile(W1, W1t, D_MODEL, FF, FF, bid%64, bid/64); return; }
  bid -= 64*16;
  tr_tile(W2, W2t, FF, D_MODEL, D_MODEL, bid%16, bid/16);
}

// ============== chunked SSD scan — MFMA, conv+SiLU fused into staging ========
__global__ __launch_bounds__(256)
void chunk_intra(const __hip_bfloat16* __restrict__ zx,
                 const float* __restrict__ cw, const float* __restrict__ cb,
                 const float* __restrict__ dt_bias,
                 const float* __restrict__ A_log, const float* __restrict__ D_skip,
                 __hip_bfloat16* __restrict__ y, __hip_bfloat16* __restrict__ Sbuf,
                 float* __restrict__ lcend, float* __restrict__ scl)
{
  __shared__ char sm[38912];
  __shared__ float s_dt[LCH], s_lc[LCH], s_wend[LCH];
  char* Cb  = sm;            // [32] rows x 272B   (8704)
  char* Bb  = sm + 8704;     // [32] x 272B        (8704)
  char* Btb = sm + 17408;    // [128] rows x 96B   (12288)  B̃^T[n][j]
  char* Xtb = sm + 29696;    // [64] rows x 96B    (6144)   X^T[p][j]
  char* Mb  = sm + 35840;    // [32] rows x 96B    (3072)   M̃[i][j]

  const int cid = blockIdx.x;
  const int c  = cid & (NCHUNK-1);
  const int bh = cid >> 6;
  const int h  = bh & 15;
  const int b  = bh >> 4;
  const int tid = threadIdx.x;
  const int t0 = c*LCH;

  if (tid < 32) {
    // fused dt: softplus(zx_dt + bias), then log-cumsum
    float A_h = -expf(A_log[h]);
    float x = __bfloat162float(zx[(size_t)(b*SEQ + t0 + tid)*D_IN_PROJ + (D_INNER + CONV_DIM) + h])
              + dt_bias[h];
    float dtv = (x > 20.f) ? x : log1pf(expf(x));
    float lc = dtv * A_h;
    #pragma unroll
    for (int d=1; d<32; d<<=1) {
      float o = __shfl_up(lc, d, 32);
      if (tid >= d) lc += o;
    }
    float lc31 = __shfl(lc, 31, 32);
    s_dt[tid] = dtv;
    s_lc[tid] = lc;
    s_wend[tid] = expf(lc31 - lc) * dtv;
    scl[cid*LCH + tid] = expf(lc);
    if (tid == 31) lcend[cid] = lc;
  }

  // conv+SiLU staging from zx: 160 threads x 2 channels x 32 rows (sliding)
  // strips: s<32 -> X (head h, local p=2s), s<96 -> B (n=2(s-32)), s<160 -> C
  if (tid < 160) {
    int loc, cc0, kind;
    if (tid < 32)      { kind=0; loc = tid*2;       cc0 = h*HEADDIM + loc; }
    else if (tid < 96) { kind=1; loc = (tid-32)*2;  cc0 = 1024 + loc; }
    else               { kind=2; loc = (tid-96)*2;  cc0 = 1152 + loc; }
    float4 wA = *(const float4*)(cw + (size_t)cc0*4);
    float4 wB = *(const float4*)(cw + (size_t)cc0*4 + 4);
    float cbA = cb[cc0], cbB = cb[cc0+1];
    const __hip_bfloat16* zb = zx + ((size_t)(b*SEQ + t0))*D_IN_PROJ + D_INNER + cc0;
    float pa3,pa2,pa1, pb3,pb2,pb1;
    if (c == 0) { pa3=pa2=pa1=pb3=pb2=pb1=0.f; }
    else {
      unsigned v3 = *(const unsigned*)(zb - 3*(ptrdiff_t)D_IN_PROJ);
      unsigned v2 = *(const unsigned*)(zb - 2*(ptrdiff_t)D_IN_PROJ);
      unsigned v1 = *(const unsigned*)(zb - 1*(ptrdiff_t)D_IN_PROJ);
      pa3=blo(v3); pb3=bhi(v3); pa2=blo(v2); pb2=bhi(v2); pa1=blo(v1); pb1=bhi(v1);
    }
    char* dstrow = (kind==1) ? Bb : Cb;
    #pragma unroll 4
    for (int r=0; r<32; ++r) {
      unsigned vc = *(const unsigned*)(zb + (size_t)r*D_IN_PROJ);
      float ca = blo(vc), cb2 = bhi(vc);
      float oa = cbA + wA.x*pa3 + wA.y*pa2 + wA.z*pa1 + wA.w*ca;
      float ob = cbB + wB.x*pb3 + wB.y*pb2 + wB.z*pb1 + wB.w*cb2;
      oa = oa * sigmoid_f(oa); ob = ob * sigmoid_f(ob);
      if (kind == 0) {
        *(unsigned short*)(Xtb + ((loc  )*48 + r)*2) = bf16bits(oa);
        *(unsigned short*)(Xtb + ((loc+1)*48 + r)*2) = bf16bits(ob);
      } else {
        *(unsigned*)(dstrow + r*272 + loc*2) = bfpack2(oa, ob);
      }
      pa3=pa2; pa2=pa1; pa1=ca; pb3=pb2; pb2=pb1; pb1=cb2;
    }
  }
  __syncthreads();   // wend + B/C/Xt ready

  // stage B̃^T[n][j] = wend_j * B[j][n] from LDS Bb
  #pragma unroll
  for (int u=0; u<2; ++u) {
    int q = tid + 256*u;
    int j = q >> 4, n8 = (q & 15)*8;
    const float w = s_wend[j];
    U4S8 bv; bv.v = *(const uint4*)(Bb + j*272 + n8*2);
    #pragma unroll
    for (int k=0;k<8;k++)
      *(unsigned short*)(Btb + ((n8+k)*48 + j)*2) = bf16bits(bf2f(bv.s[k]) * w);
  }

  const int lane = tid & 63;
  const int w    = tid >> 6;
  const int lrow = lane & 15;
  const int lkb  = (lane >> 4) * 16;
  // ---- G phase ----
  {
    const int wi = w >> 1, wj = w & 1;
    f32x4 g = (f32x4){0.f,0.f,0.f,0.f};
    const char* Ar = Cb + (wi*16 + lrow)*272 + lkb;
    const char* Br = Bb + (wj*16 + lrow)*272 + lkb;
    #pragma unroll
    for (int ks=0; ks<4; ks++){
      short8 a  = *(const short8*)(Ar + ks*64);
      short8 bb = *(const short8*)(Br + ks*64);
      g = __builtin_amdgcn_mfma_f32_16x16x32_bf16(a, bb, g, 0,0,0);
    }
    const int j = wj*16 + lrow;
    const float lcj = s_lc[j], dtj = s_dt[j];
    const float dsk = D_skip[h];
    const int i0 = wi*16 + (lane>>4)*4;
    #pragma unroll
    for (int r=0;r<4;r++){
      int i = i0 + r;
      float m = 0.f;
      if (j <= i) { m = g[r]*expf(s_lc[i]-lcj)*dtj; if (j==i) m += dsk; }
      *(unsigned short*)(Mb + (i*48 + j)*2) = bf16bits(m);
    }
  }
  __syncthreads();   // M̃ + Btb ready

  // ---- Y phase: bf16 out ----
  {
    const int it = w >> 1;
    const int pb = (w & 1)*2;
    short8 am = *(const short8*)(Mb + (it*16+lrow)*96 + lkb);
    __hip_bfloat16* ybase = y + ((size_t)(b*SEQ+t0))*D_INNER + h*HEADDIM;
    #pragma unroll
    for (int pi=0; pi<2; pi++){
      short8 xv = *(const short8*)(Xtb + ((pb+pi)*16+lrow)*96 + lkb);
      f32x4 ya = __builtin_amdgcn_mfma_f32_16x16x32_bf16(am, xv, (f32x4){0.f,0.f,0.f,0.f}, 0,0,0);
      #pragma unroll
      for (int r=0;r<4;r++){
        int i = it*16 + (lane>>4)*4 + r;
        ybase[(size_t)i*D_INNER + (pb+pi)*16 + lrow] = __float2bfloat16(ya[r]);
      }
    }
  }

  // ---- S phase ----
  f32x4 sacc[8];
  {
    short8 ax = *(const short8*)(Xtb + (w*16+lrow)*96 + lkb);
    #pragma unroll
    for (int nt=0;nt<8;nt++){
      short8 bv = *(const short8*)(Btb + (nt*16+lrow)*96 + lkb);
      sacc[nt] = __builtin_amdgcn_mfma_f32_16x16x32_bf16(ax, bv, (f32x4){0.f,0.f,0.f,0.f}, 0,0,0);
    }
  }
  __syncthreads();
  {
    const int p0b = w*16 + (lane>>4)*4;
    #pragma unroll
    for (int nt=0;nt<8;nt++){
      int n = nt*16 + lrow;
      #pragma unroll
      for (int r=0;r<4;r++)
        *(unsigned short*)(sm + (p0b+r)*272 + n*2) = bf16bits(sacc[nt][r]);
    }
  }
  __syncthreads();
  __hip_bfloat16* Sout = Sbuf + (size_t)cid*(D_STATE*HEADDIM);
  #pragma unroll
  for (int u=0;u<4;u++){
    int q = tid*4+u, row = q>>4, c8 = (q&15)*8;
    *(uint4*)(Sout + row*128 + c8) = *(const uint4*)(sm + row*272 + c8*2);
  }
}

// Kernel B: serial inter-chunk recurrence, 128 blocks, prefetch depth 2.
__global__ __launch_bounds__(256)
void state_scan(__hip_bfloat16* __restrict__ Sbuf, const float* __restrict__ lcend)
{
  const int bh = blockIdx.x >> 2;
  const int sl = blockIdx.x & 3;
  const int tid = threadIdx.x;
  uint4* Sb4 = (uint4*)Sbuf;
  const int idx0 = bh*NCHUNK*1024 + sl*256 + tid;

  float H[8];
  #pragma unroll
  for (int r=0;r<8;r++) H[r]=0.f;
  uint4 cur = Sb4[idx0];
  uint4 nx1 = Sb4[idx0 + 1024];
  float lc0 = lcend[bh*NCHUNK];
  float lc1 = lcend[bh*NCHUNK + 1];
  for (int c=0;c<NCHUNK;c++){
    uint4 nx2; float lc2;
    if (c + 2 < NCHUNK) { nx2 = Sb4[idx0 + (c+2)*1024]; lc2 = lcend[bh*NCHUNK + c + 2]; }
    else                { nx2 = make_uint4(0,0,0,0);    lc2 = 0.f; }
    float e = expf(lc0);
    uint4 o;
    o.x = bfpack2(H[0],H[1]); o.y = bfpack2(H[2],H[3]);
    o.z = bfpack2(H[4],H[5]); o.w = bfpack2(H[6],H[7]);
    Sb4[idx0 + c*1024] = o;
    H[0]=e*H[0]+blo(cur.x); H[1]=e*H[1]+bhi(cur.x);
    H[2]=e*H[2]+blo(cur.y); H[3]=e*H[3]+bhi(cur.y);
    H[4]=e*H[4]+blo(cur.z); H[5]=e*H[5]+bhi(cur.z);
    H[6]=e*H[6]+blo(cur.w); H[7]=e*H[7]+bhi(cur.w);
    cur = nx1; nx1 = nx2; lc0 = lc1; lc1 = lc2;
  }
}

// Kernel C (MFMA): y += scl_i * C_i @ H_prev.  C conv'd inline; bf16 RMW on y.
__global__ __launch_bounds__(256)
void chunk_inter(const __hip_bfloat16* __restrict__ zx,
                 const float* __restrict__ cw, const float* __restrict__ cb,
                 const __hip_bfloat16* __restrict__ Sbuf,
                 const float* __restrict__ scl, __hip_bfloat16* __restrict__ y)
{
  __shared__ char sm2[8704 + 17408];
  __shared__ float s_scl[LCH];
  char* Cb = sm2;
  char* Ht = sm2 + 8704;
  const int cid = blockIdx.x;
  const int c  = cid & (NCHUNK-1);
  const int bh = cid >> 6;
  const int h  = bh & 15;
  const int b  = bh >> 4;
  const int tid = threadIdx.x;
  const int t0 = c*LCH;

  // conv+SiLU staging of C: 64 threads x 2 channels x 32 rows (sliding)
  if (tid < 64) {
    int loc = tid*2;
    int cc0 = 1152 + loc;
    float4 wA = *(const float4*)(cw + (size_t)cc0*4);
    float4 wB = *(const float4*)(cw + (size_t)cc0*4 + 4);
    float cbA = cb[cc0], cbB = cb[cc0+1];
    const __hip_bfloat16* zb = zx + ((size_t)(b*SEQ + t0))*D_IN_PROJ + D_INNER + cc0;
    float pa3,pa2,pa1, pb3,pb2,pb1;
    if (c == 0) { pa3=pa2=pa1=pb3=pb2=pb1=0.f; }
    else {
      unsigned v3 = *(const unsigned*)(zb - 3*(ptrdiff_t)D_IN_PROJ);
      unsigned v2 = *(const unsigned*)(zb - 2*(ptrdiff_t)D_IN_PROJ);
      unsigned v1 = *(const unsigned*)(zb - 1*(ptrdiff_t)D_IN_PROJ);
      pa3=blo(v3); pb3=bhi(v3); pa2=blo(v2); pb2=bhi(v2); pa1=blo(v1); pb1=bhi(v1);
    }
    #pragma unroll 4
    for (int r=0; r<32; ++r) {
      unsigned vc = *(const unsigned*)(zb + (size_t)r*D_IN_PROJ);
      float ca = blo(vc), cb2 = bhi(vc);
      float oa = cbA + wA.x*pa3 + wA.y*pa2 + wA.z*pa1 + wA.w*ca;
      float ob = cbB + wB.x*pb3 + wB.y*pb2 + wB.z*pb1 + wB.w*cb2;
      oa = oa * sigmoid_f(oa); ob = ob * sigmoid_f(ob);
      *(unsigned*)(Cb + r*272 + loc*2) = bfpack2(oa, ob);
      pa3=pa2; pa2=pa1; pa1=ca; pb3=pb2; pb2=pb1; pb1=cb2;
    }
  }
  const uint4* Hin = (const uint4*)(Sbuf + (size_t)cid*(D_STATE*HEADDIM));
  #pragma unroll
  for (int u=0;u<4;u++){
    int q = tid*4+u, row = q>>4, c8 = (q&15)*8;
    *(uint4*)(Ht + row*272 + c8*2) = Hin[q];
  }
  if (tid < 32) s_scl[tid] = scl[cid*LCH + tid];
  __syncthreads();

  const int lane = tid & 63;
  const int w    = tid >> 6;
  const int lrow = lane & 15;
  const int lkb  = (lane >> 4) * 16;
  const int it   = w >> 1;
  const int pb   = (w & 1)*2;
  f32x4 acc[2];
  acc[0] = (f32x4){0.f,0.f,0.f,0.f};
  acc[1] = (f32x4){0.f,0.f,0.f,0.f};
  const char* Ar = Cb + (it*16+lrow)*272 + lkb;
  const char* H0 = Ht + ((pb+0)*16+lrow)*272 + lkb;
  const char* H1 = Ht + ((pb+1)*16+lrow)*272 + lkb;
  #pragma unroll
  for (int ks=0; ks<4; ks++){
    short8 a  = *(const short8*)(Ar + ks*64);
    short8 h0 = *(const short8*)(H0 + ks*64);
    short8 h1 = *(const short8*)(H1 + ks*64);
    acc[0] = __builtin_amdgcn_mfma_f32_16x16x32_bf16(a, h0, acc[0], 0,0,0);
    acc[1] = __builtin_amdgcn_mfma_f32_16x16x32_bf16(a, h1, acc[1], 0,0,0);
  }
  __hip_bfloat16* ybase = y + ((size_t)(b*SEQ+t0))*D_INNER + h*HEADDIM;
  #pragma unroll
  for (int pi=0; pi<2; pi++){
    #pragma unroll
    for (int r=0;r<4;r++){
      int i = it*16 + (lane>>4)*4 + r;
      __hip_bfloat16* yp = ybase + (size_t)i*D_INNER + (pb+pi)*16 + lrow;
      float v = __bfloat162float(*yp) + s_scl[i]*acc[pi][r];
      *yp = __float2bfloat16(v);
    }
  }
}

// ---- y*silu(z) (bf16 y,z), RMSNorm(1024)*gnorm_w -> bf16 out ----------------
__global__ __launch_bounds__(256)
void gate_rms(const __hip_bfloat16* __restrict__ zx, const float* __restrict__ gw,
              const __hip_bfloat16* __restrict__ yin, __hip_bfloat16* __restrict__ ybf)
{
  int tok = blockIdx.x;
  int c = threadIdx.x*4;
  uint2 zv2 = *(const uint2*)(zx + (size_t)tok*D_IN_PROJ + c);
  uint2 yv2 = *(const uint2*)(yin + (size_t)tok*D_INNER + c);
  float z0 = blo(zv2.x), z1 = bhi(zv2.x), z2 = blo(zv2.y), z3 = bhi(zv2.y);
  float y0 = blo(yv2.x), y1 = bhi(yv2.x), y2 = blo(yv2.y), y3 = bhi(yv2.y);
  float g0 = y0 * (z0 * sigmoid_f(z0));
  float g1 = y1 * (z1 * sigmoid_f(z1));
  float g2 = y2 * (z2 * sigmoid_f(z2));
  float g3 = y3 * (z3 * sigmoid_f(z3));
  float ss = g0*g0 + g1*g1 + g2*g2 + g3*g3;
  #pragma unroll
  for (int m=32;m>=1;m>>=1) ss += __shfl_xor(ss, m, 64);
  __shared__ float red[4];
  int wv = threadIdx.x >> 6;
  if ((threadIdx.x & 63)==0) red[wv]=ss;
  __syncthreads();
  float tot = red[0]+red[1]+red[2]+red[3];
  float sc = rsqrtf(tot*(1.f/1024.f) + 1e-5f);
  float4 gwv = *(const float4*)(gw + c);
  *(uint2*)(ybf + (size_t)tok*D_INNER + c) =
      (uint2){bfpack2(g0*sc*gwv.x, g1*sc*gwv.y), bfpack2(g2*sc*gwv.z, g3*sc*gwv.w)};
}

// ---- out = LayerNorm(sum_{z<NS} a[z] + bres) over 512; optional bf16 copy ---
template<int WBF, int NS>
__global__ __launch_bounds__(256)
void add_ln(const float* __restrict__ a, const float* __restrict__ bres,
            const float* __restrict__ gg, const float* __restrict__ bb,
            float* __restrict__ out, __hip_bfloat16* __restrict__ outbf)
{
  int tok = blockIdx.x;
  size_t o = (size_t)tok*D_MODEL;
  int c0 = threadIdx.x, c1 = threadIdx.x + 256;
  float v0 = bres[o+c0];
  float v1 = bres[o+c1];
  #pragma unroll
  for (int z=0; z<NS; ++z) {
    v0 += a[o + z*LN_SLICE + c0];
    v1 += a[o + z*LN_SLICE + c1];
  }
  float s = v0+v1, sq = v0*v0+v1*v1;
  #pragma unroll
  for (int m=32;m>=1;m>>=1){ s += __shfl_xor(s,m,64); sq += __shfl_xor(sq,m,64); }
  __shared__ float rs[4], rq[4];
  int wv = threadIdx.x>>6;
  if ((threadIdx.x&63)==0){ rs[wv]=s; rq[wv]=sq; }
  __syncthreads();
  float S = rs[0]+rs[1]+rs[2]+rs[3];
  float Q = rq[0]+rq[1]+rq[2]+rq[3];
  float mean = S*(1.f/512.f);
  float var  = Q*(1.f/512.f) - mean*mean;
  float inv  = rsqrtf(var + 1e-5f);
  float o0 = (v0-mean)*inv*gg[c0] + bb[c0];
  float o1 = (v1-mean)*inv*gg[c1] + bb[c1];
  out[o+c0] = o0;
  out[o+c1] = o1;
  if (WBF) { outbf[o+c0] = __float2bfloat16(o0); outbf[o+c1] = __float2bfloat16(o1); }
}

extern "C" void kernel_launch(void* const* d_in, const int* in_sizes, int n_in,
                              void* d_out, int out_size, void* d_ws, size_t ws_size,
                              hipStream_t stream)
{
  const float* tgt    = (const float*)d_in[0];
  const float* W_in   = (const float*)d_in[1];
  const float* conv_w = (const float*)d_in[2];
  const float* conv_b = (const float*)d_in[3];
  const float* dt_bias= (const float*)d_in[4];
  const float* A_log  = (const float*)d_in[5];
  const float* D_skip = (const float*)d_in[6];
  const float* gnorm_w= (const float*)d_in[7];
  const float* W_out  = (const float*)d_in[8];
  const float* n1_g   = (const float*)d_in[9];
  const float* n1_b   = (const float*)d_in[10];
  const float* ffn_w1 = (const float*)d_in[11];
  const float* ffn_b1 = (const float*)d_in[12];
  const float* ffn_w2 = (const float*)d_in[13];
  const float* ffn_b2 = (const float*)d_in[14];
  const float* n3_g   = (const float*)d_in[15];
  const float* n3_b   = (const float*)d_in[16];
  float* out = (float*)d_out;
  float* ws  = (float*)d_ws;

  // ---- workspace layout (float offsets) ----
  float* zxF  = ws;                                   // zx bf16 (region kept large for hmid alias)
  __hip_bfloat16* zx = (__hip_bfloat16*)zxF;
  float* xbcF = zxF + (size_t)NTOK*D_IN_PROJ;         // former xbc region (now only yb_bf alias)
  float* ybF  = xbcF + 2621440 + 65536;               // y bf16 region
  __hip_bfloat16* yb = (__hip_bfloat16*)ybF;
  float* Sreg = ybF + 4194304;                        // 8,388,608 (Sbuf bf16)
  __hip_bfloat16* Sbuf = (__hip_bfloat16*)Sreg;
  float* lcend= Sreg + 8388608;                       // 2,048
  float* scl  = lcend + NCID;                         // 65,536
  float* wreg = scl + 65536;
  __hip_bfloat16* Wint  = (__hip_bfloat16*)wreg;                   // [2432][512]
  __hip_bfloat16* Woutt = (__hip_bfloat16*)(wreg + 622592);        // [512][1024]
  __hip_bfloat16* W1t   = (__hip_bfloat16*)(wreg + 622592+262144); // [2048][512]
  __hip_bfloat16* W2t   = (__hip_bfloat16*)(wreg + 622592+262144+524288); // [512][2048]
  __hip_bfloat16* tgt_bf= (__hip_bfloat16*)(wreg + 622592+262144+524288+524288);
  float* tmp  = wreg + 622592+262144+524288+524288+1048576;  // 2 x NTOK*512 slices

  // aliases into dead regions
  __hip_bfloat16* yb_bf = (__hip_bfloat16*)xbcF;            // free region
  __hip_bfloat16* tb_bf = (__hip_bfloat16*)ybF;             // yb dead after gate_rms
  float* tb   = Sreg;                                       // Sbuf dead after chunk_inter
  __hip_bfloat16* hmid_bf = (__hip_bfloat16*)zxF;           // zx dead after gate_rms

  // 1) prep: all weight transposes + tgt->bf16 (ONE dispatch)
  prep_all<<<2048 + 76*16 + 16*32 + 64*16 + 16*64, 256, 0, stream>>>(
      tgt, tgt_bf, W_in, Wint, W_out, Woutt, ffn_w1, W1t, ffn_w2, W2t);
  // 2) in-proj (128x128) -> bf16 zx
  gemm128<0,__hip_bfloat16><<<dim3(NPJ_PAD/128, NTOK/128), 256, 0, stream>>>(
      tgt_bf, Wint, nullptr, zx, D_IN_PROJ, D_MODEL, D_IN_PROJ);
  // 3) chunked scan (conv+SiLU + dt fused into staging; y bf16)
  chunk_intra<<<NCID, 256, 0, stream>>>(zx, conv_w, conv_b, dt_bias, A_log, D_skip,
                                        yb, Sbuf, lcend, scl);
  state_scan<<<B_SZ*NHEADS*4, 256, 0, stream>>>(Sbuf, lcend);
  chunk_inter<<<NCID, 256, 0, stream>>>(zx, conv_w, conv_b, Sbuf, scl, yb);
  // 4) gate + RMSNorm -> bf16
  gate_rms<<<NTOK, 256, 0, stream>>>(zx, gnorm_w, yb, yb_bf);
  // 5) out-proj split-K=2 -> tmp[0..1]
  gemm_bf16<0,float><<<dim3(D_MODEL/64, NTOK/128, 2), 256, 0, stream>>>(
      yb_bf, Woutt, nullptr, tmp, D_MODEL, D_INNER, D_MODEL, NTOK, 2);
  // 6) tb = LayerNorm(tmp0 + tmp1 + tgt) (+ bf16 copy)
  add_ln<1,2><<<NTOK, 256, 0, stream>>>(tmp, tgt, n1_g, n1_b, tb, tb_bf);
  // 7) ffn1 (128x128, gelu) -> bf16 hmid
  gemm128<2,__hip_bfloat16><<<dim3(FF/128, NTOK/128), 256, 0, stream>>>(
      tb_bf, W1t, ffn_b1, hmid_bf, FF, D_MODEL, FF);
  // 8) ffn2 split-K=2 (+bias on z==0) -> tmp[0..1]
  gemm_bf16<1,float><<<dim3(D_MODEL/64, NTOK/128, 2), 256, 0, stream>>>(
      hmid_bf, W2t, ffn_b2, tmp, D_MODEL, FF, D_MODEL, NTOK, 2);
  // 9) out = LayerNorm(tmp0 + tmp1 + tb)
  add_ln<0,2><<<NTOK, 256, 0, stream>>>(tmp, tb, n3_g, n3_b, out, nullptr);
}

// Round 12
// 170.985 us; speedup vs baseline: 1.1716x; 1.1716x over previous
//
#include <hip/hip_runtime.h>
#include <hip/hip_bf16.h>
#include <cstddef>
#include <cstdint>

#define D_MODEL   512
#define FF        2048
#define D_STATE   128
#define D_INNER   1024
#define HEADDIM   64
#define NHEADS    16
#define CONV_DIM  1280
#define D_IN_PROJ 2320
#define NPJ_PAD   2432      // D_IN_PROJ padded to 128
#define B_SZ      2
#define SEQ       2048
#define NTOK      (B_SZ*SEQ)   // 4096
#define LCH       32
#define NCHUNK    (SEQ/LCH)    // 64
#define NCID      (B_SZ*NHEADS*NCHUNK)  // 2048
#define LN_SLICE  ((size_t)NTOK*D_MODEL)

typedef __attribute__((ext_vector_type(8))) short short8;
typedef __attribute__((ext_vector_type(4))) float f32x4;

__device__ __forceinline__ float sigmoid_f(float x){ return 1.0f/(1.0f+expf(-x)); }
__device__ __forceinline__ float gelu_f(float x){ return 0.5f*x*(1.0f+erff(x*0.70710678118654752f)); }

__device__ __forceinline__ unsigned short bf16bits(float f){
  __hip_bfloat16 h = __float2bfloat16(f);
  return *reinterpret_cast<unsigned short*>(&h);
}
__device__ __forceinline__ float bf2f(unsigned short u){ return __uint_as_float(((unsigned)u)<<16); }
__device__ __forceinline__ float blo(unsigned u){ return __uint_as_float(u<<16); }
__device__ __forceinline__ float bhi(unsigned u){ return __uint_as_float(u & 0xffff0000u); }
__device__ __forceinline__ unsigned bfpack2(float a, float b){
  return (unsigned)bf16bits(a) | ((unsigned)bf16bits(b)<<16);
}

__device__ __forceinline__ void gload16(const void* g, void* l){
  __builtin_amdgcn_global_load_lds((const __attribute__((address_space(1))) void*)g,
                                   (__attribute__((address_space(3))) void*)l, 16, 0, 0);
}

union U4S8 { uint4 v; unsigned short s[8]; };

// ============ m97-structure GEMM: BM=128,BN=128,BK=64, 4 waves of 64x64 ======
template<int EPI, typename OT>   // EPI 0: none, 1: +bias, 2: gelu(.+bias)
__global__ __launch_bounds__(256)
void gemm128(const __hip_bfloat16* __restrict__ A, const __hip_bfloat16* __restrict__ Bt,
             const float* __restrict__ bias, OT* __restrict__ C,
             int N, int K, int ldc)
{
  __shared__ char AsRaw[128*128];
  __shared__ char BsRaw[128*128];

  const int t    = threadIdx.x;
  const int bm   = blockIdx.y * 128;
  const int bn   = blockIdx.x * 128;
  const int lane = t & 63;
  const int wid  = t >> 6;
  const int wr   = wid >> 1;
  const int wc   = wid & 1;
  const int lrow = lane & 15;
  const int lkb  = (lane >> 4) * 16;
  const int sw   = (lrow & 7) << 4;

  const int rA  = t >> 3;
  const int cbA = (t & 7) * 16;
  const int scb = cbA ^ ((rA & 7) << 4);
  const size_t strideA = (size_t)K * 2;
  const char* aSrc = (const char*)A  + (size_t)(bm + rA) * strideA + scb;
  const char* bSrc = (const char*)Bt + (size_t)(bn + rA) * strideA + scb;
  char* aDst = AsRaw + wid * 1024;
  char* bDst = BsRaw + wid * 1024;

  f32x4 acc[4][4];
  #pragma unroll
  for (int m=0;m<4;m++)
    #pragma unroll
    for (int n=0;n<4;n++) acc[m][n] = (f32x4){0.f,0.f,0.f,0.f};

  const char* ArP = AsRaw + (wr*64 + lrow) * 128;
  const char* BrP = BsRaw + (wc*64 + lrow) * 128;

  for (int k0 = 0; k0 < K; k0 += 64) {
    const size_t ko = (size_t)k0 * 2;
    gload16(aSrc + ko,               aDst);
    gload16(aSrc + ko + 32*strideA,  aDst + 4096);
    gload16(aSrc + ko + 64*strideA,  aDst + 8192);
    gload16(aSrc + ko + 96*strideA,  aDst + 12288);
    gload16(bSrc + ko,               bDst);
    gload16(bSrc + ko + 32*strideA,  bDst + 4096);
    gload16(bSrc + ko + 64*strideA,  bDst + 8192);
    gload16(bSrc + ko + 96*strideA,  bDst + 12288);
    __syncthreads();
    #pragma unroll
    for (int kk = 0; kk < 2; ++kk) {
      const int kb = (kk*64 + lkb) ^ sw;
      short8 a0 = *(const short8*)(ArP + 0*2048 + kb);
      short8 a1 = *(const short8*)(ArP + 1*2048 + kb);
      short8 a2 = *(const short8*)(ArP + 2*2048 + kb);
      short8 a3 = *(const short8*)(ArP + 3*2048 + kb);
      short8 b0 = *(const short8*)(BrP + 0*2048 + kb);
      short8 b1 = *(const short8*)(BrP + 1*2048 + kb);
      short8 b2 = *(const short8*)(BrP + 2*2048 + kb);
      short8 b3 = *(const short8*)(BrP + 3*2048 + kb);
      #pragma unroll
      for (int m=0;m<4;m++){
        short8 am = (m==0)?a0:(m==1)?a1:(m==2)?a2:a3;
        acc[m][0] = __builtin_amdgcn_mfma_f32_16x16x32_bf16(am, b0, acc[m][0], 0,0,0);
        acc[m][1] = __builtin_amdgcn_mfma_f32_16x16x32_bf16(am, b1, acc[m][1], 0,0,0);
        acc[m][2] = __builtin_amdgcn_mfma_f32_16x16x32_bf16(am, b2, acc[m][2], 0,0,0);
        acc[m][3] = __builtin_amdgcn_mfma_f32_16x16x32_bf16(am, b3, acc[m][3], 0,0,0);
      }
    }
    __syncthreads();
  }

  const int orow0 = bm + wr*64 + (lane >> 4) * 4;
  const int ocol0 = bn + wc*64 + lrow;
  #pragma unroll
  for (int n=0;n<4;n++) {
    const int col = ocol0 + n*16;
    if (col >= N) continue;
    const float bv = (EPI>=1) ? bias[col] : 0.f;
    #pragma unroll
    for (int m=0;m<4;m++) {
      #pragma unroll
      for (int j=0;j<4;j++) {
        float v = acc[m][n][j] + bv;
        if (EPI==2) v = gelu_f(v);
        OT* cp = C + (size_t)(orow0 + m*16 + j)*ldc + col;
        if constexpr (sizeof(OT)==2) *cp = __float2bfloat16(v); else *cp = v;
      }
    }
  }
}

// ==== 128x64 GEMM with split-K (blockIdx.z): C_z = A[:,z*K/s:(z+1)K/s]@Bt^T ===
template<int EPI, typename OT>
__global__ __launch_bounds__(256)
void gemm_bf16(const __hip_bfloat16* __restrict__ A, const __hip_bfloat16* __restrict__ Bt,
               const float* __restrict__ bias, OT* __restrict__ C,
               int N, int K, int ldc, int M, int nsplit)
{
  __shared__ char AsRaw[128*128];
  __shared__ char BsRaw[64*128];

  const int t    = threadIdx.x;
  const int bm   = blockIdx.y * 128;
  const int bn   = blockIdx.x * 64;
  const int z    = blockIdx.z;
  const int Kloop= K / nsplit;
  A += (size_t)z * Kloop;
  Bt += (size_t)z * Kloop;
  C += (size_t)z * M * ldc;

  const int lane = t & 63;
  const int wid  = t >> 6;
  const int wr   = wid >> 1;
  const int wc   = wid & 1;
  const int lrow = lane & 15;
  const int lkb  = (lane >> 4) * 16;
  const int sw   = (lrow & 7) << 4;

  const int rA  = t >> 3;
  const int cbA = (t & 7) * 16;
  const int scb = cbA ^ ((rA & 7) << 4);
  const size_t strideA = (size_t)K * 2;
  const char* aSrc = (const char*)A  + (size_t)(bm + rA) * strideA + scb;
  const char* bSrc = (const char*)Bt + (size_t)(bn + rA) * strideA + scb;
  char* aDst = AsRaw + wid * 1024;
  char* bDst = BsRaw + wid * 1024;

  f32x4 acc[4][2];
  #pragma unroll
  for (int m=0;m<4;m++)
    #pragma unroll
    for (int n=0;n<2;n++) acc[m][n] = (f32x4){0.f,0.f,0.f,0.f};

  const char* ArP = AsRaw + (wr*64 + lrow) * 128;
  const char* BrP = BsRaw + (wc*32 + lrow) * 128;

  for (int k0 = 0; k0 < Kloop; k0 += 64) {
    const size_t ko = (size_t)k0 * 2;
    gload16(aSrc + ko,               aDst);
    gload16(aSrc + ko + 32*strideA,  aDst + 4096);
    gload16(aSrc + ko + 64*strideA,  aDst + 8192);
    gload16(aSrc + ko + 96*strideA,  aDst + 12288);
    gload16(bSrc + ko,               bDst);
    gload16(bSrc + ko + 32*strideA,  bDst + 4096);
    __syncthreads();
    #pragma unroll
    for (int kk = 0; kk < 2; ++kk) {
      const int kb = (kk*64 + lkb) ^ sw;
      short8 a0 = *(const short8*)(ArP + 0*2048 + kb);
      short8 a1 = *(const short8*)(ArP + 1*2048 + kb);
      short8 a2 = *(const short8*)(ArP + 2*2048 + kb);
      short8 a3 = *(const short8*)(ArP + 3*2048 + kb);
      short8 b0 = *(const short8*)(BrP + 0*2048 + kb);
      short8 b1 = *(const short8*)(BrP + 1*2048 + kb);
      acc[0][0] = __builtin_amdgcn_mfma_f32_16x16x32_bf16(a0, b0, acc[0][0], 0,0,0);
      acc[1][0] = __builtin_amdgcn_mfma_f32_16x16x32_bf16(a1, b0, acc[1][0], 0,0,0);
      acc[2][0] = __builtin_amdgcn_mfma_f32_16x16x32_bf16(a2, b0, acc[2][0], 0,0,0);
      acc[3][0] = __builtin_amdgcn_mfma_f32_16x16x32_bf16(a3, b0, acc[3][0], 0,0,0);
      acc[0][1] = __builtin_amdgcn_mfma_f32_16x16x32_bf16(a0, b1, acc[0][1], 0,0,0);
      acc[1][1] = __builtin_amdgcn_mfma_f32_16x16x32_bf16(a1, b1, acc[1][1], 0,0,0);
      acc[2][1] = __builtin_amdgcn_mfma_f32_16x16x32_bf16(a2, b1, acc[2][1], 0,0,0);
      acc[3][1] = __builtin_amdgcn_mfma_f32_16x16x32_bf16(a3, b1, acc[3][1], 0,0,0);
    }
    __syncthreads();
  }

  const int orow0 = bm + wr*64 + (lane >> 4) * 4;
  const int ocol0 = bn + wc*32 + lrow;
  #pragma unroll
  for (int n=0;n<2;n++) {
    const int col = ocol0 + n*16;
    if (col >= N) continue;
    const float bv = (EPI>=1 && z==0) ? bias[col] : 0.f;
    #pragma unroll
    for (int m=0;m<4;m++) {
      #pragma unroll
      for (int j=0;j<4;j++) {
        float v = acc[m][n][j] + bv;
        if (EPI==2) v = gelu_f(v);
        OT* cp = C + (size_t)(orow0 + m*16 + j)*ldc + col;
        if constexpr (sizeof(OT)==2) *cp = __float2bfloat16(v); else *cp = v;
      }
    }
  }
}

// ======= prep_all: all 4 weight transposes + tgt->bf16 in ONE dispatch =======
__device__ __forceinline__ void tr_tile(const float* __restrict__ in,
                                        __hip_bfloat16* __restrict__ out,
                                        int K, int N, int Npad, int bx, int by)
{
  __shared__ float tbuf[32][33];
  const int tx = threadIdx.x & 31, ty = threadIdx.x >> 5;
  #pragma unroll
  for (int u=0;u<4;u++){
    int k = by*32 + ty + u*8;
    int n = bx*32 + tx;
    tbuf[ty+u*8][tx] = (n < N) ? in[(size_t)k*N + n] : 0.f;
  }
  __syncthreads();
  #pragma unroll
  for (int u=0;u<4;u++){
    int n = bx*32 + ty + u*8;
    int k = by*32 + tx;
    if (n < Npad) out[(size_t)n*K + k] = __float2bfloat16(tbuf[tx][ty+u*8]);
  }
}

__global__ __launch_bounds__(256)
void prep_all(const float* __restrict__ tgt, __hip_bfloat16* __restrict__ tgt_bf,
              const float* __restrict__ W_in,  __hip_bfloat16* __restrict__ Wint,
              const float* __restrict__ W_out, __hip_bfloat16* __restrict__ Woutt,
              const float* __restrict__ W1,    __hip_bfloat16* __restrict__ W1t,
              const float* __restrict__ W2,    __hip_bfloat16* __restrict__ W2t)
{
  int bid = blockIdx.x;
  if (bid < 2048) {             // tgt convert: 2M elems, 1024/block
    int i = bid*1024 + threadIdx.x*4;
    float4 v = *(const float4*)(tgt + i);
    *(uint2*)(tgt_bf + i) = (uint2){bfpack2(v.x,v.y), bfpack2(v.z,v.w)};
    return;
  }
  bid -= 2048;
  if (bid < 76*16) { tr_tile(W_in, Wint, D_MODEL, D_IN_PROJ, NPJ_PAD, bid%76, bid/76); return; }
  bid -= 76*16;
  if (bid < 16*32) { tr_tile(W_out, Woutt, D_INNER, D_MODEL, D_MODEL, bid%16, bid/16); return; }
  bid -= 16*32;
  if (bid < 64*16) { tr_tile(W1, W1t, D_MODEL, FF, FF, bid%64, bid/64); return; }
  bid -= 64*16;
  tr_tile(W2, W2t, FF, D_MODEL, D_MODEL, bid%16, bid/16);
}

// --- depthwise causal conv(4)+SiLU (bf16 zx) -> bf16 xbc; 32-row tiles -------
__global__ __launch_bounds__(256)
void conv_silu(const __hip_bfloat16* __restrict__ zx, const float* __restrict__ cw,
               const float* __restrict__ cb, __hip_bfloat16* __restrict__ xbc)
{
  const int c  = blockIdx.x*256 + threadIdx.x;     // 0..1279
  const int t0 = blockIdx.y*32;
  const int b  = blockIdx.z;
  const float w0=cw[c*4+0], w1=cw[c*4+1], w2=cw[c*4+2], w3=cw[c*4+3];
  const float cbv = cb[c];
  const __hip_bfloat16* base = zx + ((size_t)(b*SEQ + t0))*D_IN_PROJ + D_INNER + c;
  __hip_bfloat16* obase = xbc + ((size_t)(b*SEQ + t0))*CONV_DIM + c;
  float xm3, xm2, xm1;
  if (t0 == 0) { xm3 = 0.f; xm2 = 0.f; xm1 = 0.f; }
  else {
    xm3 = __bfloat162float(base[-3*(ptrdiff_t)D_IN_PROJ]);
    xm2 = __bfloat162float(base[-2*(ptrdiff_t)D_IN_PROJ]);
    xm1 = __bfloat162float(base[-1*(ptrdiff_t)D_IN_PROJ]);
  }
  #pragma unroll 4
  for (int t=0; t<32; ++t) {
    float xc = __bfloat162float(base[(size_t)t*D_IN_PROJ]);
    float acc = cbv + w0*xm3 + w1*xm2 + w2*xm1 + w3*xc;
    obase[(size_t)t*CONV_DIM] = __float2bfloat16(acc * sigmoid_f(acc));
    xm3 = xm2; xm2 = xm1; xm1 = xc;
  }
}

// ============== chunked SSD scan — MFMA version (bf16 xbc, bf16 y) ===========
__global__ __launch_bounds__(256)
void chunk_intra(const __hip_bfloat16* __restrict__ xbc, const __hip_bfloat16* __restrict__ zx,
                 const float* __restrict__ dt_bias,
                 const float* __restrict__ A_log, const float* __restrict__ D_skip,
                 __hip_bfloat16* __restrict__ y, __hip_bfloat16* __restrict__ Sbuf,
                 float* __restrict__ lcend, float* __restrict__ scl)
{
  __shared__ char sm[38912];
  __shared__ float s_dt[LCH], s_lc[LCH], s_wend[LCH];
  char* Cb  = sm;            // [32] rows x 272B   (8704)
  char* Bb  = sm + 8704;     // [32] x 272B        (8704)
  char* Btb = sm + 17408;    // [128] rows x 96B   (12288)  B̃^T[n][j]
  char* Xtb = sm + 29696;    // [64] rows x 96B    (6144)   X^T[p][j]
  char* Mb  = sm + 35840;    // [32] rows x 96B    (3072)   M̃[i][j]

  const int cid = blockIdx.x;
  const int c  = cid & (NCHUNK-1);
  const int bh = cid >> 6;
  const int h  = bh & 15;
  const int b  = bh >> 4;
  const int tid = threadIdx.x;
  const int t0 = c*LCH;
  const __hip_bfloat16* rowbase = xbc + ((size_t)(b*SEQ + t0))*CONV_DIM;

  if (tid < 32) {
    // fused dt: softplus(zx_dt + bias), then log-cumsum
    float A_h = -expf(A_log[h]);
    float x = __bfloat162float(zx[(size_t)(b*SEQ + t0 + tid)*D_IN_PROJ + (D_INNER + CONV_DIM) + h])
              + dt_bias[h];
    float dtv = (x > 20.f) ? x : log1pf(expf(x));
    float lc = dtv * A_h;
    #pragma unroll
    for (int d=1; d<32; d<<=1) {
      float o = __shfl_up(lc, d, 32);
      if (tid >= d) lc += o;
    }
    float lc31 = __shfl(lc, 31, 32);
    s_dt[tid] = dtv;
    s_lc[tid] = lc;
    s_wend[tid] = expf(lc31 - lc) * dtv;
    scl[cid*LCH + tid] = expf(lc);
    if (tid == 31) lcend[cid] = lc;
  }

  #pragma unroll
  for (int u=0; u<2; ++u) {
    int q = tid + 256*u;
    int r = q >> 4, c8 = (q & 15)*8;
    const __hip_bfloat16* rp = rowbase + (size_t)r*CONV_DIM + D_INNER;
    *(uint4*)(Bb + r*272 + c8*2) = *(const uint4*)(rp + c8);
    *(uint4*)(Cb + r*272 + c8*2) = *(const uint4*)(rp + D_STATE + c8);
  }
  {
    int j = tid >> 3, p0 = (tid & 7)*8;
    U4S8 xv; xv.v = *(const uint4*)(rowbase + (size_t)j*CONV_DIM + h*HEADDIM + p0);
    #pragma unroll
    for (int k=0;k<8;k++)
      *(unsigned short*)(Xtb + ((p0+k)*48 + j)*2) = xv.s[k];
  }
  __syncthreads();   // wend + B/C/Xt ready

  // stage B̃^T[n][j] = wend_j * B[j][n] from LDS Bb
  #pragma unroll
  for (int u=0; u<2; ++u) {
    int q = tid + 256*u;
    int j = q >> 4, n8 = (q & 15)*8;
    const float w = s_wend[j];
    U4S8 bv; bv.v = *(const uint4*)(Bb + j*272 + n8*2);
    #pragma unroll
    for (int k=0;k<8;k++)
      *(unsigned short*)(Btb + ((n8+k)*48 + j)*2) = bf16bits(bf2f(bv.s[k]) * w);
  }

  const int lane = tid & 63;
  const int w    = tid >> 6;
  const int lrow = lane & 15;
  const int lkb  = (lane >> 4) * 16;
  // ---- G phase ----
  {
    const int wi = w >> 1, wj = w & 1;
    f32x4 g = (f32x4){0.f,0.f,0.f,0.f};
    const char* Ar = Cb + (wi*16 + lrow)*272 + lkb;
    const char* Br = Bb + (wj*16 + lrow)*272 + lkb;
    #pragma unroll
    for (int ks=0; ks<4; ks++){
      short8 a  = *(const short8*)(Ar + ks*64);
      short8 bb = *(const short8*)(Br + ks*64);
      g = __builtin_amdgcn_mfma_f32_16x16x32_bf16(a, bb, g, 0,0,0);
    }
    const int j = wj*16 + lrow;
    const float lcj = s_lc[j], dtj = s_dt[j];
    const float dsk = D_skip[h];
    const int i0 = wi*16 + (lane>>4)*4;
    #pragma unroll
    for (int r=0;r<4;r++){
      int i = i0 + r;
      float m = 0.f;
      if (j <= i) { m = g[r]*expf(s_lc[i]-lcj)*dtj; if (j==i) m += dsk; }
      *(unsigned short*)(Mb + (i*48 + j)*2) = bf16bits(m);
    }
  }
  __syncthreads();   // M̃ + Btb ready

  // ---- Y phase: bf16 out ----
  {
    const int it = w >> 1;
    const int pb = (w & 1)*2;
    short8 am = *(const short8*)(Mb + (it*16+lrow)*96 + lkb);
    __hip_bfloat16* ybase = y + ((size_t)(b*SEQ+t0))*D_INNER + h*HEADDIM;
    #pragma unroll
    for (int pi=0; pi<2; pi++){
      short8 xv = *(const short8*)(Xtb + ((pb+pi)*16+lrow)*96 + lkb);
      f32x4 ya = __builtin_amdgcn_mfma_f32_16x16x32_bf16(am, xv, (f32x4){0.f,0.f,0.f,0.f}, 0,0,0);
      #pragma unroll
      for (int r=0;r<4;r++){
        int i = it*16 + (lane>>4)*4 + r;
        ybase[(size_t)i*D_INNER + (pb+pi)*16 + lrow] = __float2bfloat16(ya[r]);
      }
    }
  }

  // ---- S phase ----
  f32x4 sacc[8];
  {
    short8 ax = *(const short8*)(Xtb + (w*16+lrow)*96 + lkb);
    #pragma unroll
    for (int nt=0;nt<8;nt++){
      short8 bv = *(const short8*)(Btb + (nt*16+lrow)*96 + lkb);
      sacc[nt] = __builtin_amdgcn_mfma_f32_16x16x32_bf16(ax, bv, (f32x4){0.f,0.f,0.f,0.f}, 0,0,0);
    }
  }
  __syncthreads();
  {
    const int p0b = w*16 + (lane>>4)*4;
    #pragma unroll
    for (int nt=0;nt<8;nt++){
      int n = nt*16 + lrow;
      #pragma unroll
      for (int r=0;r<4;r++)
        *(unsigned short*)(sm + (p0b+r)*272 + n*2) = bf16bits(sacc[nt][r]);
    }
  }
  __syncthreads();
  __hip_bfloat16* Sout = Sbuf + (size_t)cid*(D_STATE*HEADDIM);
  #pragma unroll
  for (int u=0;u<4;u++){
    int q = tid*4+u, row = q>>4, c8 = (q&15)*8;
    *(uint4*)(Sout + row*128 + c8) = *(const uint4*)(sm + row*272 + c8*2);
  }
}

// Kernel B: serial inter-chunk recurrence, 128 blocks, prefetch depth 2.
__global__ __launch_bounds__(256)
void state_scan(__hip_bfloat16* __restrict__ Sbuf, const float* __restrict__ lcend)
{
  const int bh = blockIdx.x >> 2;
  const int sl = blockIdx.x & 3;
  const int tid = threadIdx.x;
  uint4* Sb4 = (uint4*)Sbuf;
  const int idx0 = bh*NCHUNK*1024 + sl*256 + tid;

  float H[8];
  #pragma unroll
  for (int r=0;r<8;r++) H[r]=0.f;
  uint4 cur = Sb4[idx0];
  uint4 nx1 = Sb4[idx0 + 1024];
  float lc0 = lcend[bh*NCHUNK];
  float lc1 = lcend[bh*NCHUNK + 1];
  for (int c=0;c<NCHUNK;c++){
    uint4 nx2; float lc2;
    if (c + 2 < NCHUNK) { nx2 = Sb4[idx0 + (c+2)*1024]; lc2 = lcend[bh*NCHUNK + c + 2]; }
    else                { nx2 = make_uint4(0,0,0,0);    lc2 = 0.f; }
    float e = expf(lc0);
    uint4 o;
    o.x = bfpack2(H[0],H[1]); o.y = bfpack2(H[2],H[3]);
    o.z = bfpack2(H[4],H[5]); o.w = bfpack2(H[6],H[7]);
    Sb4[idx0 + c*1024] = o;
    H[0]=e*H[0]+blo(cur.x); H[1]=e*H[1]+bhi(cur.x);
    H[2]=e*H[2]+blo(cur.y); H[3]=e*H[3]+bhi(cur.y);
    H[4]=e*H[4]+blo(cur.z); H[5]=e*H[5]+bhi(cur.z);
    H[6]=e*H[6]+blo(cur.w); H[7]=e*H[7]+bhi(cur.w);
    cur = nx1; nx1 = nx2; lc0 = lc1; lc1 = lc2;
  }
}

// Kernel C (MFMA): y += scl_i * C_i @ H_prev.  bf16 RMW on y.
__global__ __launch_bounds__(256)
void chunk_inter(const __hip_bfloat16* __restrict__ xbc, const __hip_bfloat16* __restrict__ Sbuf,
                 const float* __restrict__ scl, __hip_bfloat16* __restrict__ y)
{
  __shared__ char sm2[8704 + 17408];
  __shared__ float s_scl[LCH];
  char* Cb = sm2;
  char* Ht = sm2 + 8704;
  const int cid = blockIdx.x;
  const int c  = cid & (NCHUNK-1);
  const int bh = cid >> 6;
  const int h  = bh & 15;
  const int b  = bh >> 4;
  const int tid = threadIdx.x;
  const int t0 = c*LCH;
  const __hip_bfloat16* rowbase = xbc + ((size_t)(b*SEQ + t0))*CONV_DIM;

  #pragma unroll
  for (int u=0;u<2;u++){
    int q = tid + 256*u;
    int r = q >> 4, c8 = (q & 15)*8;
    *(uint4*)(Cb + r*272 + c8*2) = *(const uint4*)(rowbase + (size_t)r*CONV_DIM + D_INNER + D_STATE + c8);
  }
  const uint4* Hin = (const uint4*)(Sbuf + (size_t)cid*(D_STATE*HEADDIM));
  #pragma unroll
  for (int u=0;u<4;u++){
    int q = tid*4+u, row = q>>4, c8 = (q&15)*8;
    *(uint4*)(Ht + row*272 + c8*2) = Hin[q];
  }
  if (tid < 32) s_scl[tid] = scl[cid*LCH + tid];
  __syncthreads();

  const int lane = tid & 63;
  const int w    = tid >> 6;
  const int lrow = lane & 15;
  const int lkb  = (lane >> 4) * 16;
  const int it   = w >> 1;
  const int pb   = (w & 1)*2;
  f32x4 acc[2];
  acc[0] = (f32x4){0.f,0.f,0.f,0.f};
  acc[1] = (f32x4){0.f,0.f,0.f,0.f};
  const char* Ar = Cb + (it*16+lrow)*272 + lkb;
  const char* H0 = Ht + ((pb+0)*16+lrow)*272 + lkb;
  const char* H1 = Ht + ((pb+1)*16+lrow)*272 + lkb;
  #pragma unroll
  for (int ks=0; ks<4; ks++){
    short8 a  = *(const short8*)(Ar + ks*64);
    short8 h0 = *(const short8*)(H0 + ks*64);
    short8 h1 = *(const short8*)(H1 + ks*64);
    acc[0] = __builtin_amdgcn_mfma_f32_16x16x32_bf16(a, h0, acc[0], 0,0,0);
    acc[1] = __builtin_amdgcn_mfma_f32_16x16x32_bf16(a, h1, acc[1], 0,0,0);
  }
  __hip_bfloat16* ybase = y + ((size_t)(b*SEQ+t0))*D_INNER + h*HEADDIM;
  #pragma unroll
  for (int pi=0; pi<2; pi++){
    #pragma unroll
    for (int r=0;r<4;r++){
      int i = it*16 + (lane>>4)*4 + r;
      __hip_bfloat16* yp = ybase + (size_t)i*D_INNER + (pb+pi)*16 + lrow;
      float v = __bfloat162float(*yp) + s_scl[i]*acc[pi][r];
      *yp = __float2bfloat16(v);
    }
  }
}

// ---- y*silu(z) (bf16 y,z), RMSNorm(1024)*gnorm_w -> bf16 out ----------------
__global__ __launch_bounds__(256)
void gate_rms(const __hip_bfloat16* __restrict__ zx, const float* __restrict__ gw,
              const __hip_bfloat16* __restrict__ yin, __hip_bfloat16* __restrict__ ybf)
{
  int tok = blockIdx.x;
  int c = threadIdx.x*4;
  uint2 zv2 = *(const uint2*)(zx + (size_t)tok*D_IN_PROJ + c);
  uint2 yv2 = *(const uint2*)(yin + (size_t)tok*D_INNER + c);
  float z0 = blo(zv2.x), z1 = bhi(zv2.x), z2 = blo(zv2.y), z3 = bhi(zv2.y);
  float y0 = blo(yv2.x), y1 = bhi(yv2.x), y2 = blo(yv2.y), y3 = bhi(yv2.y);
  float g0 = y0 * (z0 * sigmoid_f(z0));
  float g1 = y1 * (z1 * sigmoid_f(z1));
  float g2 = y2 * (z2 * sigmoid_f(z2));
  float g3 = y3 * (z3 * sigmoid_f(z3));
  float ss = g0*g0 + g1*g1 + g2*g2 + g3*g3;
  #pragma unroll
  for (int m=32;m>=1;m>>=1) ss += __shfl_xor(ss, m, 64);
  __shared__ float red[4];
  int wv = threadIdx.x >> 6;
  if ((threadIdx.x & 63)==0) red[wv]=ss;
  __syncthreads();
  float tot = red[0]+red[1]+red[2]+red[3];
  float sc = rsqrtf(tot*(1.f/1024.f) + 1e-5f);
  float4 gwv = *(const float4*)(gw + c);
  *(uint2*)(ybf + (size_t)tok*D_INNER + c) =
      (uint2){bfpack2(g0*sc*gwv.x, g1*sc*gwv.y), bfpack2(g2*sc*gwv.z, g3*sc*gwv.w)};
}

// ---- out = LayerNorm(sum_{z<NS} a[z] + bres) over 512; optional bf16 copy ---
template<int WBF, int NS>
__global__ __launch_bounds__(256)
void add_ln(const float* __restrict__ a, const float* __restrict__ bres,
            const float* __restrict__ gg, const float* __restrict__ bb,
            float* __restrict__ out, __hip_bfloat16* __restrict__ outbf)
{
  int tok = blockIdx.x;
  size_t o = (size_t)tok*D_MODEL;
  int c0 = threadIdx.x, c1 = threadIdx.x + 256;
  float v0 = bres[o+c0];
  float v1 = bres[o+c1];
  #pragma unroll
  for (int z=0; z<NS; ++z) {
    v0 += a[o + z*LN_SLICE + c0];
    v1 += a[o + z*LN_SLICE + c1];
  }
  float s = v0+v1, sq = v0*v0+v1*v1;
  #pragma unroll
  for (int m=32;m>=1;m>>=1){ s += __shfl_xor(s,m,64); sq += __shfl_xor(sq,m,64); }
  __shared__ float rs[4], rq[4];
  int wv = threadIdx.x>>6;
  if ((threadIdx.x&63)==0){ rs[wv]=s; rq[wv]=sq; }
  __syncthreads();
  float S = rs[0]+rs[1]+rs[2]+rs[3];
  float Q = rq[0]+rq[1]+rq[2]+rq[3];
  float mean = S*(1.f/512.f);
  float var  = Q*(1.f/512.f) - mean*mean;
  float inv  = rsqrtf(var + 1e-5f);
  float o0 = (v0-mean)*inv*gg[c0] + bb[c0];
  float o1 = (v1-mean)*inv*gg[c1] + bb[c1];
  out[o+c0] = o0;
  out[o+c1] = o1;
  if (WBF) { outbf[o+c0] = __float2bfloat16(o0); outbf[o+c1] = __float2bfloat16(o1); }
}

extern "C" void kernel_launch(void* const* d_in, const int* in_sizes, int n_in,
                              void* d_out, int out_size, void* d_ws, size_t ws_size,
                              hipStream_t stream)
{
  const float* tgt    = (const float*)d_in[0];
  const float* W_in   = (const float*)d_in[1];
  const float* conv_w = (const float*)d_in[2];
  const float* conv_b = (const float*)d_in[3];
  const float* dt_bias= (const float*)d_in[4];
  const float* A_log  = (const float*)d_in[5];
  const float* D_skip = (const float*)d_in[6];
  const float* gnorm_w= (const float*)d_in[7];
  const float* W_out  = (const float*)d_in[8];
  const float* n1_g   = (const float*)d_in[9];
  const float* n1_b   = (const float*)d_in[10];
  const float* ffn_w1 = (const float*)d_in[11];
  const float* ffn_b1 = (const float*)d_in[12];
  const float* ffn_w2 = (const float*)d_in[13];
  const float* ffn_b2 = (const float*)d_in[14];
  const float* n3_g   = (const float*)d_in[15];
  const float* n3_b   = (const float*)d_in[16];
  float* out = (float*)d_out;
  float* ws  = (float*)d_ws;

  // ---- workspace layout (float offsets) ----
  float* zxF  = ws;                                   // zx bf16 (region kept large for hmid alias)
  __hip_bfloat16* zx = (__hip_bfloat16*)zxF;
  float* xbcF = zxF + (size_t)NTOK*D_IN_PROJ;         // 2,621,440 (bf16 xbc)
  __hip_bfloat16* xbc = (__hip_bfloat16*)xbcF;
  float* ybF  = xbcF + 2621440 + 65536;               // y bf16 region
  __hip_bfloat16* yb = (__hip_bfloat16*)ybF;
  float* Sreg = ybF + 4194304;                        // 8,388,608 (Sbuf bf16)
  __hip_bfloat16* Sbuf = (__hip_bfloat16*)Sreg;
  float* lcend= Sreg + 8388608;                       // 2,048
  float* scl  = lcend + NCID;                         // 65,536
  float* wreg = scl + 65536;
  __hip_bfloat16* Wint  = (__hip_bfloat16*)wreg;                   // [2432][512]
  __hip_bfloat16* Woutt = (__hip_bfloat16*)(wreg + 622592);        // [512][1024]
  __hip_bfloat16* W1t   = (__hip_bfloat16*)(wreg + 622592+262144); // [2048][512]
  __hip_bfloat16* W2t   = (__hip_bfloat16*)(wreg + 622592+262144+524288); // [512][2048]
  __hip_bfloat16* tgt_bf= (__hip_bfloat16*)(wreg + 622592+262144+524288+524288);
  float* tmp  = wreg + 622592+262144+524288+524288+1048576;  // 2 x NTOK*512 slices

  // aliases into dead regions
  __hip_bfloat16* yb_bf = (__hip_bfloat16*)xbcF;            // xbc dead after chunk_inter
  __hip_bfloat16* tb_bf = (__hip_bfloat16*)ybF;             // yb dead after gate_rms
  float* tb   = Sreg;                                       // Sbuf dead after chunk_inter
  __hip_bfloat16* hmid_bf = (__hip_bfloat16*)zxF;           // zx dead after gate_rms

  // 1) prep: all weight transposes + tgt->bf16 (ONE dispatch)
  prep_all<<<2048 + 76*16 + 16*32 + 64*16 + 16*64, 256, 0, stream>>>(
      tgt, tgt_bf, W_in, Wint, W_out, Woutt, ffn_w1, W1t, ffn_w2, W2t);
  // 2) in-proj (128x128) -> bf16 zx
  gemm128<0,__hip_bfloat16><<<dim3(NPJ_PAD/128, NTOK/128), 256, 0, stream>>>(
      tgt_bf, Wint, nullptr, zx, D_IN_PROJ, D_MODEL, D_IN_PROJ);
  // 3) conv + SiLU -> bf16 xbc (32-row tiles)
  conv_silu<<<dim3(CONV_DIM/256, SEQ/32, B_SZ), 256, 0, stream>>>(zx, conv_w, conv_b, xbc);
  // 4) chunked scan (dt fused into intra prologue; y bf16)
  chunk_intra<<<NCID, 256, 0, stream>>>(xbc, zx, dt_bias, A_log, D_skip, yb, Sbuf, lcend, scl);
  state_scan<<<B_SZ*NHEADS*4, 256, 0, stream>>>(Sbuf, lcend);
  chunk_inter<<<NCID, 256, 0, stream>>>(xbc, Sbuf, scl, yb);
  // 5) gate + RMSNorm -> bf16
  gate_rms<<<NTOK, 256, 0, stream>>>(zx, gnorm_w, yb, yb_bf);
  // 6) out-proj split-K=2 -> tmp[0..1]
  gemm_bf16<0,float><<<dim3(D_MODEL/64, NTOK/128, 2), 256, 0, stream>>>(
      yb_bf, Woutt, nullptr, tmp, D_MODEL, D_INNER, D_MODEL, NTOK, 2);
  // 7) tb = LayerNorm(tmp0 + tmp1 + tgt) (+ bf16 copy)
  add_ln<1,2><<<NTOK, 256, 0, stream>>>(tmp, tgt, n1_g, n1_b, tb, tb_bf);
  // 8) ffn1 (128x128, gelu) -> bf16 hmid
  gemm128<2,__hip_bfloat16><<<dim3(FF/128, NTOK/128), 256, 0, stream>>>(
      tb_bf, W1t, ffn_b1, hmid_bf, FF, D_MODEL, FF);
  // 9) ffn2 split-K=2 (+bias on z==0) -> tmp[0..1]
  gemm_bf16<1,float><<<dim3(D_MODEL/64, NTOK/128, 2), 256, 0, stream>>>(
      hmid_bf, W2t, ffn_b2, tmp, D_MODEL, FF, D_MODEL, NTOK, 2);
  // 10) out = LayerNorm(tmp0 + tmp1 + tb)
  add_ln<0,2><<<NTOK, 256, 0, stream>>>(tmp, tb, n3_g, n3_b, out, nullptr);
}